// Round 1
// baseline (5779.208 us; speedup 1.0000x reference)
//
#include <hip/hip_runtime.h>
#include <math.h>

#define NN 50000
#define NE 800000
#define D 128
#define NBATCH 32
#define NLAYERS 3
#define TE 32
#define TN 16

__device__ __forceinline__ float silu_f(float x) {
    return x / (1.0f + __expf(-x));
}

// ---------------- time MLP: tp[B,D] ----------------
__global__ void k_time_mlp(const float* __restrict__ te,
                           const float* __restrict__ w1, const float* __restrict__ b1,
                           const float* __restrict__ w2, const float* __restrict__ b2,
                           float* __restrict__ tp) {
    __shared__ float s_in[D];
    __shared__ float s_hid[D];
    const int b = blockIdx.x;
    const int j = threadIdx.x;
    s_in[j] = te[b * D + j];
    __syncthreads();
    float acc = b1[j];
    for (int k = 0; k < D; ++k) acc = fmaf(s_in[k], w1[k * D + j], acc);
    s_hid[j] = silu_f(acc);
    __syncthreads();
    float acc2 = b2[j];
    for (int k = 0; k < D; ++k) acc2 = fmaf(s_hid[k], w2[k * D + j], acc2);
    tp[b * D + j] = acc2;
}

// ---------------- h = x + tp[batch] ----------------
__global__ void k_init_h(const float* __restrict__ x, const float* __restrict__ tp,
                         const int* __restrict__ batch, float* __restrict__ h) {
    int idx = blockIdx.x * 256 + threadIdx.x;
    int n = idx >> 7, c = idx & 127;
    h[idx] = x[idx] + tp[batch[n] * D + c];
}

// ---------------- degree (targets = col) ----------------
__global__ void k_deg(const int* __restrict__ col, float* __restrict__ deg) {
    int e = blockIdx.x * 256 + threadIdx.x;
    unsafeAtomicAdd(&deg[col[e]], 1.0f);
}

// ---------------- per-edge distance ----------------
__global__ void k_dist(const int* __restrict__ ei, const float* __restrict__ pos,
                       float* __restrict__ dist) {
    int e = blockIdx.x * 256 + threadIdx.x;
    int r = ei[e], c = ei[NE + e];
    float dx = pos[r * 3 + 0] - pos[c * 3 + 0];
    float dy = pos[r * 3 + 1] - pos[c * 3 + 1];
    float dz = pos[r * 3 + 2] - pos[c * 3 + 2];
    dist[e] = sqrtf(dx * dx + dy * dy + dz * dz);
}

// ---------------- fused edge MLP + scatter ----------------
// block: 256 threads, TE=32 edges. thread (eg,cg): 4 edges x 4 cols register tile.
__global__ __launch_bounds__(256, 2)
void k_edge(const float* __restrict__ h,
            const int* __restrict__ ei,
            const float* __restrict__ dist,
            const float* __restrict__ w1, const float* __restrict__ b1,
            const float* __restrict__ w2, const float* __restrict__ b2,
            float* __restrict__ agg) {
    __shared__ float sHC[TE][D + 4];   // h[col[e]] (target, x_i)
    __shared__ float sHR[TE][D + 4];   // h[row[e]] (source, x_j)
    __shared__ float sHid[TE][D + 4];
    __shared__ float sB[16 * D];
    __shared__ float sDist[TE];
    __shared__ int sCol[TE], sRow[TE];

    const int t = threadIdx.x;
    const int ebase = blockIdx.x * TE;

    if (t < TE) {
        int e = ebase + t;
        sRow[t] = ei[e];
        sCol[t] = ei[NE + e];
        sDist[t] = dist[e];
    }
    __syncthreads();
    for (int f = t; f < TE * 32; f += 256) {
        int ee = f >> 5, q = f & 31;
        ((float4*)&sHC[ee][0])[q] = ((const float4*)(h + (size_t)sCol[ee] * D))[q];
        ((float4*)&sHR[ee][0])[q] = ((const float4*)(h + (size_t)sRow[ee] * D))[q];
    }

    const int eg = t >> 5;          // 0..7
    const int cg = t & 31;          // 0..31
    const int e0 = eg * 4, c0 = cg * 4;

    float acc[4][4] = {};

    #pragma unroll
    for (int half = 0; half < 2; ++half) {
        const float (*A)[D + 4] = half ? sHR : sHC;
        const float* Wb = w1 + half * D * D;
        for (int kc = 0; kc < D; kc += 16) {
            __syncthreads();
            ((float4*)sB)[t]       = ((const float4*)(Wb + kc * D))[t];
            ((float4*)sB)[t + 256] = ((const float4*)(Wb + kc * D))[t + 256];
            __syncthreads();
            #pragma unroll
            for (int kk = 0; kk < 16; ++kk) {
                const float4 bv = *(const float4*)(sB + kk * D + c0);
                float a0 = A[e0 + 0][kc + kk];
                float a1 = A[e0 + 1][kc + kk];
                float a2 = A[e0 + 2][kc + kk];
                float a3 = A[e0 + 3][kc + kk];
                acc[0][0] = fmaf(a0, bv.x, acc[0][0]);
                acc[0][1] = fmaf(a0, bv.y, acc[0][1]);
                acc[0][2] = fmaf(a0, bv.z, acc[0][2]);
                acc[0][3] = fmaf(a0, bv.w, acc[0][3]);
                acc[1][0] = fmaf(a1, bv.x, acc[1][0]);
                acc[1][1] = fmaf(a1, bv.y, acc[1][1]);
                acc[1][2] = fmaf(a1, bv.z, acc[1][2]);
                acc[1][3] = fmaf(a1, bv.w, acc[1][3]);
                acc[2][0] = fmaf(a2, bv.x, acc[2][0]);
                acc[2][1] = fmaf(a2, bv.y, acc[2][1]);
                acc[2][2] = fmaf(a2, bv.z, acc[2][2]);
                acc[2][3] = fmaf(a2, bv.w, acc[2][3]);
                acc[3][0] = fmaf(a3, bv.x, acc[3][0]);
                acc[3][1] = fmaf(a3, bv.y, acc[3][1]);
                acc[3][2] = fmaf(a3, bv.z, acc[3][2]);
                acc[3][3] = fmaf(a3, bv.w, acc[3][3]);
            }
        }
    }

    // dist column (W1 row 256) + bias + silu -> sHid
    {
        const float4 wd = *(const float4*)(w1 + 256 * D + c0);
        const float4 b1v = *(const float4*)(b1 + c0);
        #pragma unroll
        for (int i = 0; i < 4; ++i) {
            float dd = sDist[e0 + i];
            sHid[e0 + i][c0 + 0] = silu_f(acc[i][0] + dd * wd.x + b1v.x);
            sHid[e0 + i][c0 + 1] = silu_f(acc[i][1] + dd * wd.y + b1v.y);
            sHid[e0 + i][c0 + 2] = silu_f(acc[i][2] + dd * wd.z + b1v.z);
            sHid[e0 + i][c0 + 3] = silu_f(acc[i][3] + dd * wd.w + b1v.w);
        }
    }

    float acc2[4][4] = {};
    for (int kc = 0; kc < D; kc += 16) {
        __syncthreads();
        ((float4*)sB)[t]       = ((const float4*)(w2 + kc * D))[t];
        ((float4*)sB)[t + 256] = ((const float4*)(w2 + kc * D))[t + 256];
        __syncthreads();
        #pragma unroll
        for (int kk = 0; kk < 16; ++kk) {
            const float4 bv = *(const float4*)(sB + kk * D + c0);
            float a0 = sHid[e0 + 0][kc + kk];
            float a1 = sHid[e0 + 1][kc + kk];
            float a2 = sHid[e0 + 2][kc + kk];
            float a3 = sHid[e0 + 3][kc + kk];
            acc2[0][0] = fmaf(a0, bv.x, acc2[0][0]);
            acc2[0][1] = fmaf(a0, bv.y, acc2[0][1]);
            acc2[0][2] = fmaf(a0, bv.z, acc2[0][2]);
            acc2[0][3] = fmaf(a0, bv.w, acc2[0][3]);
            acc2[1][0] = fmaf(a1, bv.x, acc2[1][0]);
            acc2[1][1] = fmaf(a1, bv.y, acc2[1][1]);
            acc2[1][2] = fmaf(a1, bv.z, acc2[1][2]);
            acc2[1][3] = fmaf(a1, bv.w, acc2[1][3]);
            acc2[2][0] = fmaf(a2, bv.x, acc2[2][0]);
            acc2[2][1] = fmaf(a2, bv.y, acc2[2][1]);
            acc2[2][2] = fmaf(a2, bv.z, acc2[2][2]);
            acc2[2][3] = fmaf(a2, bv.w, acc2[2][3]);
            acc2[3][0] = fmaf(a3, bv.x, acc2[3][0]);
            acc2[3][1] = fmaf(a3, bv.y, acc2[3][1]);
            acc2[3][2] = fmaf(a3, bv.z, acc2[3][2]);
            acc2[3][3] = fmaf(a3, bv.w, acc2[3][3]);
        }
    }

    const float4 b2v = *(const float4*)(b2 + c0);
    #pragma unroll
    for (int i = 0; i < 4; ++i) {
        float* dst = agg + (size_t)sCol[e0 + i] * D + c0;
        unsafeAtomicAdd(dst + 0, acc2[i][0] + b2v.x);
        unsafeAtomicAdd(dst + 1, acc2[i][1] + b2v.y);
        unsafeAtomicAdd(dst + 2, acc2[i][2] + b2v.z);
        unsafeAtomicAdd(dst + 3, acc2[i][3] + b2v.w);
    }
}

// ---------------- fused node MLP + residual + layernorm (in-place h) ----------------
__global__ __launch_bounds__(256, 2)
void k_node(const float* h,
            const float* __restrict__ agg, const float* __restrict__ deg,
            const float* __restrict__ w1, const float* __restrict__ b1,
            const float* __restrict__ w2, const float* __restrict__ b2,
            const float* __restrict__ lng, const float* __restrict__ lnb,
            float* hout) {
    __shared__ float sH[TN][D + 4];
    __shared__ float sHid[TN][D + 4];
    __shared__ float sY[TN][D + 4];
    __shared__ float sB[16 * D];

    const int t = threadIdx.x;
    const int nbase = blockIdx.x * TN;

    for (int f = t; f < TN * 32; f += 256) {
        int nn = f >> 5, q = f & 31;
        ((float4*)&sH[nn][0])[q] = ((const float4*)(h + (size_t)(nbase + nn) * D))[q];
    }

    const int ng = t >> 5;      // 0..7 -> nodes ng*2, ng*2+1
    const int cg = t & 31;
    const int c0 = cg * 4;

    float acc[2][4] = {};
    for (int kc = 0; kc < D; kc += 16) {
        __syncthreads();
        ((float4*)sB)[t]       = ((const float4*)(w1 + kc * D))[t];
        ((float4*)sB)[t + 256] = ((const float4*)(w1 + kc * D))[t + 256];
        __syncthreads();
        #pragma unroll
        for (int kk = 0; kk < 16; ++kk) {
            const float4 bv = *(const float4*)(sB + kk * D + c0);
            float a0 = sH[ng * 2 + 0][kc + kk];
            float a1 = sH[ng * 2 + 1][kc + kk];
            acc[0][0] = fmaf(a0, bv.x, acc[0][0]);
            acc[0][1] = fmaf(a0, bv.y, acc[0][1]);
            acc[0][2] = fmaf(a0, bv.z, acc[0][2]);
            acc[0][3] = fmaf(a0, bv.w, acc[0][3]);
            acc[1][0] = fmaf(a1, bv.x, acc[1][0]);
            acc[1][1] = fmaf(a1, bv.y, acc[1][1]);
            acc[1][2] = fmaf(a1, bv.z, acc[1][2]);
            acc[1][3] = fmaf(a1, bv.w, acc[1][3]);
        }
    }
    {
        const float4 b1v = *(const float4*)(b1 + c0);
        sHid[ng * 2 + 0][c0 + 0] = silu_f(acc[0][0] + b1v.x);
        sHid[ng * 2 + 0][c0 + 1] = silu_f(acc[0][1] + b1v.y);
        sHid[ng * 2 + 0][c0 + 2] = silu_f(acc[0][2] + b1v.z);
        sHid[ng * 2 + 0][c0 + 3] = silu_f(acc[0][3] + b1v.w);
        sHid[ng * 2 + 1][c0 + 0] = silu_f(acc[1][0] + b1v.x);
        sHid[ng * 2 + 1][c0 + 1] = silu_f(acc[1][1] + b1v.y);
        sHid[ng * 2 + 1][c0 + 2] = silu_f(acc[1][2] + b1v.z);
        sHid[ng * 2 + 1][c0 + 3] = silu_f(acc[1][3] + b1v.w);
    }

    float acc2[2][4] = {};
    for (int kc = 0; kc < D; kc += 16) {
        __syncthreads();
        ((float4*)sB)[t]       = ((const float4*)(w2 + kc * D))[t];
        ((float4*)sB)[t + 256] = ((const float4*)(w2 + kc * D))[t + 256];
        __syncthreads();
        #pragma unroll
        for (int kk = 0; kk < 16; ++kk) {
            const float4 bv = *(const float4*)(sB + kk * D + c0);
            float a0 = sHid[ng * 2 + 0][kc + kk];
            float a1 = sHid[ng * 2 + 1][kc + kk];
            acc2[0][0] = fmaf(a0, bv.x, acc2[0][0]);
            acc2[0][1] = fmaf(a0, bv.y, acc2[0][1]);
            acc2[0][2] = fmaf(a0, bv.z, acc2[0][2]);
            acc2[0][3] = fmaf(a0, bv.w, acc2[0][3]);
            acc2[1][0] = fmaf(a1, bv.x, acc2[1][0]);
            acc2[1][1] = fmaf(a1, bv.y, acc2[1][1]);
            acc2[1][2] = fmaf(a1, bv.z, acc2[1][2]);
            acc2[1][3] = fmaf(a1, bv.w, acc2[1][3]);
        }
    }

    {
        const float4 b2v = *(const float4*)(b2 + c0);
        #pragma unroll
        for (int i = 0; i < 2; ++i) {
            int node = nbase + ng * 2 + i;
            float inv = 1.0f / fmaxf(deg[node], 1.0f);
            const float* ag = agg + (size_t)node * D + c0;
            sY[ng * 2 + i][c0 + 0] = sH[ng * 2 + i][c0 + 0] + acc2[i][0] + b2v.x + ag[0] * inv;
            sY[ng * 2 + i][c0 + 1] = sH[ng * 2 + i][c0 + 1] + acc2[i][1] + b2v.y + ag[1] * inv;
            sY[ng * 2 + i][c0 + 2] = sH[ng * 2 + i][c0 + 2] + acc2[i][2] + b2v.z + ag[2] * inv;
            sY[ng * 2 + i][c0 + 3] = sH[ng * 2 + i][c0 + 3] + acc2[i][3] + b2v.w + ag[3] * inv;
        }
    }
    __syncthreads();

    // layernorm: 16 threads per node
    const int nid = t >> 4, l16 = t & 15;
    float s = 0.f, s2 = 0.f;
    #pragma unroll
    for (int i = 0; i < 8; ++i) {
        float v = sY[nid][l16 + 16 * i];
        s += v; s2 += v * v;
    }
    #pragma unroll
    for (int off = 8; off; off >>= 1) {
        s  += __shfl_xor(s, off);
        s2 += __shfl_xor(s2, off);
    }
    float mean = s * (1.0f / D);
    float var  = s2 * (1.0f / D) - mean * mean;
    float rstd = rsqrtf(var + 1e-5f);
    #pragma unroll
    for (int i = 0; i < 8; ++i) {
        int c = l16 + 16 * i;
        float v = (sY[nid][c] - mean) * rstd * lng[c] + lnb[c];
        hout[(size_t)(nbase + nid) * D + c] = v;
    }
}

extern "C" void kernel_launch(void* const* d_in, const int* in_sizes, int n_in,
                              void* d_out, int out_size, void* d_ws, size_t ws_size,
                              hipStream_t stream) {
    const float* x        = (const float*)d_in[0];
    const float* pos      = (const float*)d_in[1];
    const float* time_emb = (const float*)d_in[2];
    const float* time_w1  = (const float*)d_in[3];
    const float* time_b1  = (const float*)d_in[4];
    const float* time_w2  = (const float*)d_in[5];
    const float* time_b2  = (const float*)d_in[6];
    const float* node_w1  = (const float*)d_in[7];
    const float* node_b1  = (const float*)d_in[8];
    const float* node_w2  = (const float*)d_in[9];
    const float* node_b2  = (const float*)d_in[10];
    const float* edge_w1  = (const float*)d_in[11];
    const float* edge_b1  = (const float*)d_in[12];
    const float* edge_w2  = (const float*)d_in[13];
    const float* edge_b2  = (const float*)d_in[14];
    const float* ln_g     = (const float*)d_in[15];
    const float* ln_b     = (const float*)d_in[16];
    const int*   ei       = (const int*)d_in[17];
    const int*   batch    = (const int*)d_in[18];

    float* h = (float*)d_out;                       // [NN, D]
    float* pos_out = h + (size_t)NN * D;            // [NN, 3]

    char* w = (char*)d_ws;
    float* tp   = (float*)w;  w += (((size_t)NBATCH * D * 4) + 255) & ~(size_t)255;
    float* deg  = (float*)w;  w += (((size_t)NN * 4) + 255) & ~(size_t)255;
    float* dist = (float*)w;  w += (((size_t)NE * 4) + 255) & ~(size_t)255;
    float* agg  = (float*)w;  w += (((size_t)NN * D * 4) + 255) & ~(size_t)255;

    hipMemsetAsync(deg, 0, (size_t)NN * 4, stream);
    k_time_mlp<<<NBATCH, D, 0, stream>>>(time_emb, time_w1, time_b1, time_w2, time_b2, tp);
    k_init_h<<<(NN * D) / 256, 256, 0, stream>>>(x, tp, batch, h);
    k_deg<<<NE / 256, 256, 0, stream>>>(ei + NE, deg);
    k_dist<<<NE / 256, 256, 0, stream>>>(ei, pos, dist);

    for (int l = 0; l < NLAYERS; ++l) {
        hipMemsetAsync(agg, 0, (size_t)NN * D * 4, stream);
        k_edge<<<NE / TE, 256, 0, stream>>>(h, ei, dist,
            edge_w1 + (size_t)l * (2 * D + 1) * D, edge_b1 + (size_t)l * D,
            edge_w2 + (size_t)l * D * D, edge_b2 + (size_t)l * D, agg);
        k_node<<<NN / TN, 256, 0, stream>>>(h, agg, deg,
            node_w1 + (size_t)l * D * D, node_b1 + (size_t)l * D,
            node_w2 + (size_t)l * D * D, node_b2 + (size_t)l * D,
            ln_g + (size_t)l * D, ln_b + (size_t)l * D, h);
    }
    hipMemcpyAsync(pos_out, pos, (size_t)NN * 3 * 4, hipMemcpyDeviceToDevice, stream);
}

// Round 2
// 1726.222 us; speedup vs baseline: 3.3479x; 3.3479x over previous
//
#include <hip/hip_runtime.h>
#include <hip/hip_bf16.h>
#include <math.h>

#define NN 50000
#define NE 800000
#define D 128
#define NBATCH 32
#define NLAYERS 3

typedef __attribute__((ext_vector_type(8))) short bf16x8;
typedef __attribute__((ext_vector_type(4))) float f32x4;

__device__ __forceinline__ float silu_f(float x) {
    return x / (1.0f + __expf(-x));
}

__device__ __forceinline__ ushort f2b(float v) {
    __hip_bfloat16 b = __float2bfloat16(v);
    return *(ushort*)&b;
}

// ---------------- time MLP: tp[B,D] ----------------
__global__ void k_time_mlp(const float* __restrict__ te,
                           const float* __restrict__ w1, const float* __restrict__ b1,
                           const float* __restrict__ w2, const float* __restrict__ b2,
                           float* __restrict__ tp) {
    __shared__ float s_in[D];
    __shared__ float s_hid[D];
    const int b = blockIdx.x;
    const int j = threadIdx.x;
    s_in[j] = te[b * D + j];
    __syncthreads();
    float acc = b1[j];
    for (int k = 0; k < D; ++k) acc = fmaf(s_in[k], w1[k * D + j], acc);
    s_hid[j] = silu_f(acc);
    __syncthreads();
    float acc2 = b2[j];
    for (int k = 0; k < D; ++k) acc2 = fmaf(s_hid[k], w2[k * D + j], acc2);
    tp[b * D + j] = acc2;
}

// ---------------- h = x + tp[batch]; also h_bf16 ----------------
__global__ void k_init_h(const float* __restrict__ x, const float* __restrict__ tp,
                         const int* __restrict__ batch, float* __restrict__ h,
                         ushort* __restrict__ hb) {
    int idx = blockIdx.x * 256 + threadIdx.x;
    int n = idx >> 7, c = idx & 127;
    float v = x[idx] + tp[batch[n] * D + c];
    h[idx] = v;
    hb[idx] = f2b(v);
}

// ---------------- degree (targets = col) ----------------
__global__ void k_deg(const int* __restrict__ col, float* __restrict__ deg) {
    int e = blockIdx.x * 256 + threadIdx.x;
    unsafeAtomicAdd(&deg[col[e]], 1.0f);
}

// ---------------- per-edge distance ----------------
__global__ void k_dist(const int* __restrict__ ei, const float* __restrict__ pos,
                       float* __restrict__ dist) {
    int e = blockIdx.x * 256 + threadIdx.x;
    int r = ei[e], c = ei[NE + e];
    float dx = pos[r * 3 + 0] - pos[c * 3 + 0];
    float dy = pos[r * 3 + 1] - pos[c * 3 + 1];
    float dz = pos[r * 3 + 2] - pos[c * 3 + 2];
    dist[e] = sqrtf(dx * dx + dy * dy + dz * dz);
}

// ---------------- weight pre-pack into fragment-major bf16 ----------------
// out[l][ct][ks][lane][j] = bf16( W[l][ ks*32 + (lane>>4)*8 + j ][ ct*16 + (lane&15) ] )
__global__ void k_pack(const float* __restrict__ W, ushort* __restrict__ out,
                       int KSlog2, int layerStrideW, int totalPerLayer) {
    int t = blockIdx.x * 256 + threadIdx.x;
    int l = t / totalPerLayer;
    int r = t - l * totalPerLayer;
    int j = r & 7;
    int lane = (r >> 3) & 63;
    int ks = (r >> 9) & ((1 << KSlog2) - 1);
    int ct = r >> (9 + KSlog2);
    int k = ks * 32 + ((lane >> 4) << 3) + j;
    int n = ct * 16 + (lane & 15);
    out[t] = f2b(W[(size_t)l * layerStrideW + k * 128 + n]);
}

// ---------------- fused edge MLP (MFMA) + scatter ----------------
// 256 threads = 4 waves, 64 edges/block; wave w owns edges [w*16, w*16+16).
__global__ __launch_bounds__(256, 3)
void k_edge(const ushort* __restrict__ hb,
            const int* __restrict__ ei,
            const float* __restrict__ dist,
            const ushort* __restrict__ pw1, const ushort* __restrict__ pw2,
            const float* __restrict__ w1f, const float* __restrict__ b1,
            const float* __restrict__ b2,
            float* __restrict__ agg) {
    __shared__ ushort sA[64 * 256];    // [edge][256] concat(h_col, h_row), 16B-chunk swizzled
    __shared__ ushort sHid[64 * 128];  // hidden activations, swizzled
    __shared__ int sCol[64], sRow[64];
    __shared__ float sDist[64];

    const int t = threadIdx.x;
    const int ebase = blockIdx.x * 64;

    if (t < 64) {
        int e = ebase + t;
        sRow[t] = ei[e];
        sCol[t] = ei[NE + e];
        sDist[t] = dist[e];
    }
    __syncthreads();

    // gather h_bf16 rows: 64 edges x 32 chunks of 16B (chunks 0-15 = h[col], 16-31 = h[row])
    #pragma unroll
    for (int i = 0; i < 8; ++i) {
        int f = t + i * 256;
        int e = f >> 5, c = f & 31;
        int node = (c < 16) ? sCol[e] : sRow[e];
        bf16x8 v = *(const bf16x8*)(hb + (size_t)node * D + (c & 15) * 8);
        *(bf16x8*)(&sA[e * 256 + ((c ^ (e & 7)) * 8)]) = v;
    }
    __syncthreads();

    const int lane = t & 63;
    const int wv = t >> 6;
    const int we0 = wv * 16;          // wave's edge-row base within tile
    const int lane16 = lane & 15;
    const int lg = lane >> 4;
    const int ar = we0 + lane16;      // A row this lane reads

    // ---- GEMM1: [64 x 256] @ W1[256 x 128] ----
    f32x4 acc[8];
    #pragma unroll
    for (int ct = 0; ct < 8; ++ct) acc[ct] = (f32x4){0.f, 0.f, 0.f, 0.f};

    #pragma unroll
    for (int ks = 0; ks < 8; ++ks) {
        int c = ks * 4 + lg;
        bf16x8 a = *(const bf16x8*)(&sA[ar * 256 + ((c ^ (ar & 7)) * 8)]);
        #pragma unroll
        for (int ct = 0; ct < 8; ++ct) {
            bf16x8 b = *(const bf16x8*)(pw1 + (((ct * 8 + ks) * 64 + lane) * 8));
            acc[ct] = __builtin_amdgcn_mfma_f32_16x16x32_bf16(a, b, acc[ct], 0, 0, 0);
        }
    }

    // epilogue 1: + dist * w1[256,:] + b1, silu, -> sHid (bf16, swizzled)
    #pragma unroll
    for (int ct = 0; ct < 8; ++ct) {
        int col = ct * 16 + lane16;
        float wd = w1f[256 * D + col];
        float b1v = b1[col];
        #pragma unroll
        for (int r = 0; r < 4; ++r) {
            int er = we0 + lg * 4 + r;
            float v = acc[ct][r] + sDist[er] * wd + b1v;
            v = silu_f(v);
            int c2 = col >> 3;
            sHid[er * 128 + ((c2 ^ (er & 7)) * 8) + (col & 7)] = f2b(v);
        }
    }
    // wave-local only: each wave reads back rows it wrote itself (compiler inserts lgkmcnt)

    // ---- GEMM2: [64 x 128] @ W2[128 x 128] ----
    f32x4 acc2[8];
    #pragma unroll
    for (int ct = 0; ct < 8; ++ct) acc2[ct] = (f32x4){0.f, 0.f, 0.f, 0.f};

    #pragma unroll
    for (int ks = 0; ks < 4; ++ks) {
        int c = ks * 4 + lg;
        bf16x8 a = *(const bf16x8*)(&sHid[ar * 128 + ((c ^ (ar & 7)) * 8)]);
        #pragma unroll
        for (int ct = 0; ct < 8; ++ct) {
            bf16x8 b = *(const bf16x8*)(pw2 + (((ct * 4 + ks) * 64 + lane) * 8));
            acc2[ct] = __builtin_amdgcn_mfma_f32_16x16x32_bf16(a, b, acc2[ct], 0, 0, 0);
        }
    }

    // epilogue 2: + b2, scatter-add to agg[target]
    #pragma unroll
    for (int ct = 0; ct < 8; ++ct) {
        int col = ct * 16 + lane16;
        float b2v = b2[col];
        #pragma unroll
        for (int r = 0; r < 4; ++r) {
            int er = we0 + lg * 4 + r;
            int node = sCol[er];
            unsafeAtomicAdd(agg + (size_t)node * D + col, acc2[ct][r] + b2v);
        }
    }
}

// ---------------- fused node MLP (MFMA) + residual + layernorm ----------------
// 256 threads = 4 waves, 64 nodes/block.
__global__ __launch_bounds__(256, 3)
void k_node(const float* __restrict__ h, const ushort* __restrict__ hbin,
            const float* __restrict__ agg, const float* __restrict__ deg,
            const ushort* __restrict__ pw1, const ushort* __restrict__ pw2,
            const float* __restrict__ b1, const float* __restrict__ b2,
            const float* __restrict__ lng, const float* __restrict__ lnb,
            float* __restrict__ hout, ushort* __restrict__ hbout) {
    __shared__ ushort sA[64 * 128];
    __shared__ ushort sHid[64 * 128];

    const int t = threadIdx.x;
    const int nbase = blockIdx.x * 64;

    #pragma unroll
    for (int i = 0; i < 4; ++i) {
        int f = t + i * 256;
        int row = f >> 4, c = f & 15;
        int node = nbase + row; if (node >= NN) node = NN - 1;
        bf16x8 v = *(const bf16x8*)(hbin + (size_t)node * D + c * 8);
        *(bf16x8*)(&sA[row * 128 + ((c ^ (row & 7)) * 8)]) = v;
    }
    __syncthreads();

    const int lane = t & 63;
    const int wv = t >> 6;
    const int we0 = wv * 16;
    const int lane16 = lane & 15;
    const int lg = lane >> 4;
    const int ar = we0 + lane16;

    f32x4 acc[8];
    #pragma unroll
    for (int ct = 0; ct < 8; ++ct) acc[ct] = (f32x4){0.f, 0.f, 0.f, 0.f};

    #pragma unroll
    for (int ks = 0; ks < 4; ++ks) {
        int c = ks * 4 + lg;
        bf16x8 a = *(const bf16x8*)(&sA[ar * 128 + ((c ^ (ar & 7)) * 8)]);
        #pragma unroll
        for (int ct = 0; ct < 8; ++ct) {
            bf16x8 b = *(const bf16x8*)(pw1 + (((ct * 4 + ks) * 64 + lane) * 8));
            acc[ct] = __builtin_amdgcn_mfma_f32_16x16x32_bf16(a, b, acc[ct], 0, 0, 0);
        }
    }

    #pragma unroll
    for (int ct = 0; ct < 8; ++ct) {
        int col = ct * 16 + lane16;
        float b1v = b1[col];
        #pragma unroll
        for (int r = 0; r < 4; ++r) {
            int er = we0 + lg * 4 + r;
            float v = silu_f(acc[ct][r] + b1v);
            int c2 = col >> 3;
            sHid[er * 128 + ((c2 ^ (er & 7)) * 8) + (col & 7)] = f2b(v);
        }
    }

    f32x4 acc2[8];
    #pragma unroll
    for (int ct = 0; ct < 8; ++ct) acc2[ct] = (f32x4){0.f, 0.f, 0.f, 0.f};

    #pragma unroll
    for (int ks = 0; ks < 4; ++ks) {
        int c = ks * 4 + lg;
        bf16x8 a = *(const bf16x8*)(&sHid[ar * 128 + ((c ^ (ar & 7)) * 8)]);
        #pragma unroll
        for (int ct = 0; ct < 8; ++ct) {
            bf16x8 b = *(const bf16x8*)(pw2 + (((ct * 4 + ks) * 64 + lane) * 8));
            acc2[ct] = __builtin_amdgcn_mfma_f32_16x16x32_bf16(a, b, acc2[ct], 0, 0, 0);
        }
    }

    // y = h + nodeMLP(h) + b2 + agg/deg   (stored back into acc2)
    #pragma unroll
    for (int ct = 0; ct < 8; ++ct) {
        int col = ct * 16 + lane16;
        float b2v = b2[col];
        #pragma unroll
        for (int r = 0; r < 4; ++r) {
            int er = we0 + lg * 4 + r;
            int node = nbase + er;
            int nc = node < NN ? node : NN - 1;
            float invd = 1.0f / fmaxf(deg[nc], 1.0f);
            float y = h[(size_t)nc * D + col] + acc2[ct][r] + b2v
                    + agg[(size_t)nc * D + col] * invd;
            acc2[ct][r] = y;
        }
    }

    // layernorm per row: 16-lane group holds the row's 128 values (8 per lane per r)
    #pragma unroll
    for (int r = 0; r < 4; ++r) {
        float s = 0.f, s2 = 0.f;
        #pragma unroll
        for (int ct = 0; ct < 8; ++ct) { float y = acc2[ct][r]; s += y; s2 += y * y; }
        #pragma unroll
        for (int off = 1; off < 16; off <<= 1) {
            s  += __shfl_xor(s,  off, 16);
            s2 += __shfl_xor(s2, off, 16);
        }
        float mean = s * (1.0f / D);
        float var  = s2 * (1.0f / D) - mean * mean;
        float rstd = rsqrtf(var + 1e-5f);
        int er = we0 + lg * 4 + r;
        int node = nbase + er;
        if (node < NN) {
            #pragma unroll
            for (int ct = 0; ct < 8; ++ct) {
                int col = ct * 16 + lane16;
                float v = (acc2[ct][r] - mean) * rstd * lng[col] + lnb[col];
                hout[(size_t)node * D + col] = v;
                hbout[(size_t)node * D + col] = f2b(v);
            }
        }
    }
}

extern "C" void kernel_launch(void* const* d_in, const int* in_sizes, int n_in,
                              void* d_out, int out_size, void* d_ws, size_t ws_size,
                              hipStream_t stream) {
    const float* x        = (const float*)d_in[0];
    const float* pos      = (const float*)d_in[1];
    const float* time_emb = (const float*)d_in[2];
    const float* time_w1  = (const float*)d_in[3];
    const float* time_b1  = (const float*)d_in[4];
    const float* time_w2  = (const float*)d_in[5];
    const float* time_b2  = (const float*)d_in[6];
    const float* node_w1  = (const float*)d_in[7];
    const float* node_b1  = (const float*)d_in[8];
    const float* node_w2  = (const float*)d_in[9];
    const float* node_b2  = (const float*)d_in[10];
    const float* edge_w1  = (const float*)d_in[11];
    const float* edge_b1  = (const float*)d_in[12];
    const float* edge_w2  = (const float*)d_in[13];
    const float* edge_b2  = (const float*)d_in[14];
    const float* ln_g     = (const float*)d_in[15];
    const float* ln_b     = (const float*)d_in[16];
    const int*   ei       = (const int*)d_in[17];
    const int*   batch    = (const int*)d_in[18];

    float* h = (float*)d_out;                       // [NN, D]
    float* pos_out = h + (size_t)NN * D;            // [NN, 3]

    char* w = (char*)d_ws;
    float*  tp    = (float*)w;  w += (((size_t)NBATCH * D * 4) + 255) & ~(size_t)255;
    float*  deg   = (float*)w;  w += (((size_t)NN * 4) + 255) & ~(size_t)255;
    float*  dist  = (float*)w;  w += (((size_t)NE * 4) + 255) & ~(size_t)255;
    float*  agg   = (float*)w;  w += (((size_t)NN * D * 4) + 255) & ~(size_t)255;
    ushort* hb    = (ushort*)w; w += (((size_t)NN * D * 2) + 255) & ~(size_t)255;
    ushort* pwE1  = (ushort*)w; w += (((size_t)NLAYERS * 32768 * 2) + 255) & ~(size_t)255;
    ushort* pwE2  = (ushort*)w; w += (((size_t)NLAYERS * 16384 * 2) + 255) & ~(size_t)255;
    ushort* pwN1  = (ushort*)w; w += (((size_t)NLAYERS * 16384 * 2) + 255) & ~(size_t)255;
    ushort* pwN2  = (ushort*)w; w += (((size_t)NLAYERS * 16384 * 2) + 255) & ~(size_t)255;

    hipMemsetAsync(deg, 0, (size_t)NN * 4, stream);
    k_time_mlp<<<NBATCH, D, 0, stream>>>(time_emb, time_w1, time_b1, time_w2, time_b2, tp);
    k_init_h<<<(NN * D) / 256, 256, 0, stream>>>(x, tp, batch, h, hb);
    k_deg<<<NE / 256, 256, 0, stream>>>(ei + NE, deg);
    k_dist<<<NE / 256, 256, 0, stream>>>(ei, pos, dist);

    // weight pre-pack (fragment-major bf16)
    k_pack<<<(NLAYERS * 32768) / 256, 256, 0, stream>>>(edge_w1, pwE1, 3, 257 * 128, 32768);
    k_pack<<<(NLAYERS * 16384) / 256, 256, 0, stream>>>(edge_w2, pwE2, 2, 128 * 128, 16384);
    k_pack<<<(NLAYERS * 16384) / 256, 256, 0, stream>>>(node_w1, pwN1, 2, 128 * 128, 16384);
    k_pack<<<(NLAYERS * 16384) / 256, 256, 0, stream>>>(node_w2, pwN2, 2, 128 * 128, 16384);

    for (int l = 0; l < NLAYERS; ++l) {
        hipMemsetAsync(agg, 0, (size_t)NN * D * 4, stream);
        k_edge<<<NE / 64, 256, 0, stream>>>(hb, ei, dist,
            pwE1 + (size_t)l * 32768, pwE2 + (size_t)l * 16384,
            edge_w1 + (size_t)l * (2 * D + 1) * D, edge_b1 + (size_t)l * D,
            edge_b2 + (size_t)l * D, agg);
        k_node<<<(NN + 63) / 64, 256, 0, stream>>>(h, hb, agg, deg,
            pwN1 + (size_t)l * 16384, pwN2 + (size_t)l * 16384,
            node_b1 + (size_t)l * D, node_b2 + (size_t)l * D,
            ln_g + (size_t)l * D, ln_b + (size_t)l * D, h, hb);
    }
    hipMemcpyAsync(pos_out, pos, (size_t)NN * 3 * 4, hipMemcpyDeviceToDevice, stream);
}